// Round 16
// baseline (141.317 us; speedup 1.0000x reference)
//
#include <hip/hip_runtime.h>
#include <hip/hip_bf16.h>
#include <cstdint>

// Problem: B=32, T1=T2=512, D=128, gamma=1.0
// out[b] = softDTW( 1 - cos_sim(x[b], y[b]) )
//
// ws layout (floats):
//   skew : 32*1023*512 = 16,760,832   (cost/ln2 in anti-diagonal layout)

#define BT      32
#define TLEN    512
#define DF      128
#define NDIAG   1023          // kd = 0..1022  (kd = i-1 + j-1)
#define BIGV    1e30f
#define INV_LN2 1.44269504088896340f
#define LN2     0.69314718055994531f

// ------------------------------------------------- cosine-dist GEMM -> skew
// (R15, measured good: 64x128 tile, 1024 blocks = 4 blocks/CU, fused norms.)
#define KC    32
#define SPADX 68
#define SPADY 132

__global__ __launch_bounds__(256) void sdtw_gemm_skew(const float* __restrict__ x,
                                                      const float* __restrict__ y,
                                                      float* __restrict__ skew) {
    __shared__ float smem[8320];             // max(stage 6400, epi 8320)
    __shared__ float rsx[64], rsy[128];      // row/col sumsq
    float* xs = smem;                        // [KC][SPADX]: xs[k][row], 64 rows
    float* ys = smem + KC * SPADX;           // [KC][SPADY]: ys[k][col], 128 cols

    const int b  = blockIdx.z;
    const int r0 = blockIdx.y * 64;
    const int c0 = blockIdx.x * 128;
    const int tid = threadIdx.x;
    const int tx = tid & 15, ty = tid >> 4;

    const float* xb = x + ((size_t)b * TLEN + r0) * DF;
    const float* yb = y + ((size_t)b * TLEN + c0) * DF;

    float acc[4][8];
    #pragma unroll
    for (int i = 0; i < 4; ++i)
        #pragma unroll
        for (int j = 0; j < 8; ++j) acc[i][j] = 0.0f;

    float psx[2] = {0, 0}, psy[4] = {0, 0, 0, 0};

    float4 rx[2], ry[4];
    #pragma unroll
    for (int i = 0; i < 2; ++i) {
        int g = tid + i * 256, row = g >> 3, kq = g & 7;
        rx[i] = *reinterpret_cast<const float4*>(xb + (size_t)row * DF + kq * 4);
    }
    #pragma unroll
    for (int i = 0; i < 4; ++i) {
        int g = tid + i * 256, row = g >> 3, kq = g & 7;
        ry[i] = *reinterpret_cast<const float4*>(yb + (size_t)row * DF + kq * 4);
    }

    for (int kb = 0; kb < DF; kb += KC) {
        __syncthreads();
        #pragma unroll
        for (int i = 0; i < 2; ++i) {
            int g = tid + i * 256, row = g >> 3, kq = g & 7;
            xs[(kq * 4 + 0) * SPADX + row] = rx[i].x;
            xs[(kq * 4 + 1) * SPADX + row] = rx[i].y;
            xs[(kq * 4 + 2) * SPADX + row] = rx[i].z;
            xs[(kq * 4 + 3) * SPADX + row] = rx[i].w;
            psx[i] = fmaf(rx[i].x, rx[i].x, psx[i]);
            psx[i] = fmaf(rx[i].y, rx[i].y, psx[i]);
            psx[i] = fmaf(rx[i].z, rx[i].z, psx[i]);
            psx[i] = fmaf(rx[i].w, rx[i].w, psx[i]);
        }
        #pragma unroll
        for (int i = 0; i < 4; ++i) {
            int g = tid + i * 256, row = g >> 3, kq = g & 7;
            ys[(kq * 4 + 0) * SPADY + row] = ry[i].x;
            ys[(kq * 4 + 1) * SPADY + row] = ry[i].y;
            ys[(kq * 4 + 2) * SPADY + row] = ry[i].z;
            ys[(kq * 4 + 3) * SPADY + row] = ry[i].w;
            psy[i] = fmaf(ry[i].x, ry[i].x, psy[i]);
            psy[i] = fmaf(ry[i].y, ry[i].y, psy[i]);
            psy[i] = fmaf(ry[i].z, ry[i].z, psy[i]);
            psy[i] = fmaf(ry[i].w, ry[i].w, psy[i]);
        }
        __syncthreads();
        if (kb + KC < DF) {
            #pragma unroll
            for (int i = 0; i < 2; ++i) {
                int g = tid + i * 256, row = g >> 3, kq = g & 7;
                rx[i] = *reinterpret_cast<const float4*>(xb + (size_t)row * DF + (kb + KC) + kq * 4);
            }
            #pragma unroll
            for (int i = 0; i < 4; ++i) {
                int g = tid + i * 256, row = g >> 3, kq = g & 7;
                ry[i] = *reinterpret_cast<const float4*>(yb + (size_t)row * DF + (kb + KC) + kq * 4);
            }
        }
        #pragma unroll
        for (int k = 0; k < KC; ++k) {
            float ax[4], ay[8];
            *reinterpret_cast<float4*>(&ax[0]) = *reinterpret_cast<const float4*>(&xs[k * SPADX + ty * 4]);
            *reinterpret_cast<float4*>(&ay[0]) = *reinterpret_cast<const float4*>(&ys[k * SPADY + tx * 8]);
            *reinterpret_cast<float4*>(&ay[4]) = *reinterpret_cast<const float4*>(&ys[k * SPADY + tx * 8 + 4]);
            #pragma unroll
            for (int i = 0; i < 4; ++i)
                #pragma unroll
                for (int j = 0; j < 8; ++j)
                    acc[i][j] = fmaf(ax[i], ay[j], acc[i][j]);
        }
    }

    #pragma unroll
    for (int o = 1; o <= 4; o <<= 1) {
        psx[0] += __shfl_xor(psx[0], o);
        psx[1] += __shfl_xor(psx[1], o);
        psy[0] += __shfl_xor(psy[0], o);
        psy[1] += __shfl_xor(psy[1], o);
        psy[2] += __shfl_xor(psy[2], o);
        psy[3] += __shfl_xor(psy[3], o);
    }
    if ((tid & 7) == 0) {
        #pragma unroll
        for (int i = 0; i < 2; ++i) rsx[(tid + i * 256) >> 3] = psx[i];
        #pragma unroll
        for (int i = 0; i < 4; ++i) rsy[(tid + i * 256) >> 3] = psy[i];
    }

    __syncthreads();
    float rn[4], cn[8];
    #pragma unroll
    for (int i = 0; i < 4; ++i) rn[i] = 1.0f / fmaxf(sqrtf(rsx[ty * 4 + i]), 1e-12f);
    #pragma unroll
    for (int j = 0; j < 8; ++j) cn[j] = 1.0f / fmaxf(sqrtf(rsy[tx * 8 + j]), 1e-12f);

    float* cs = smem;                        // [64][130], reuses staging space
    #pragma unroll
    for (int i = 0; i < 4; ++i)
        #pragma unroll
        for (int j = 0; j < 8; ++j)
            cs[(ty * 4 + i) * 130 + tx * 8 + j] =
                (1.0f - acc[i][j] * rn[i] * cn[j]) * INV_LN2;
    __syncthreads();

    float* sk = skew + (size_t)b * (NDIAG * TLEN);
    const int wv = tid >> 6, l = tid & 63;
    for (int dd = wv; dd < 191; dd += 4) {
        int lo = max(0, dd - 127), hi = min(63, dd);
        int rl = lo + l;
        if (rl <= hi)
            sk[(size_t)(r0 + c0 + dd) * TLEN + r0 + rl] = cs[rl * 129 + dd];  // rl*130+(dd-rl)
    }
}

// ----------------------------------------------------------------- DTW DP
// R16: same structure as R9/R14 (8 waves, stagger-16, segment modes, DPP
// lane-0 patch, hoisted quads) but the per-segment __syncthreads is replaced
// by a RAW barrier: sched_barrier + s_waitcnt lgkmcnt(0) + s_barrier.
// Rationale: __syncthreads emits s_waitcnt vmcnt(0) lgkmcnt(0), draining
// the per-lane-PRIVATE cost prefetches (the phase-15 load is ~0 cy old at
// the barrier -> ~250-400 cy L2 stall per segment for nothing). Only the
// lane-63 ds_write quads have cross-wave semantics -> lgkmcnt(0) suffices.
// Cost loads now stay in flight across barriers; consumption 8 phases
// (~1400 cy) after issue via compiler-counted vmcnt(N).

__device__ __forceinline__ int clampi(int v) {
    return v < 0 ? 0 : (v > NDIAG - 1 ? NDIAG - 1 : v);
}

__device__ __forceinline__ float dpp_shr1_old(float old, float x) {
    return __builtin_bit_cast(float,
        __builtin_amdgcn_update_dpp(__builtin_bit_cast(int, old),
                                    __builtin_bit_cast(int, x),
                                    0x138 /*wave_shr:1*/, 0xF, 0xF, false));
}

__device__ __forceinline__ void seg_barrier_lds_only() {
    __builtin_amdgcn_sched_barrier(0);
    asm volatile("s_waitcnt lgkmcnt(0)" ::: "memory");
    __builtin_amdgcn_s_barrier();
    __builtin_amdgcn_sched_barrier(0);
}

#define PH(s, CC, PN, PO, NQC, MASKED, CLAMPED)                                \
  {                                                                            \
    float up_ = dpp_shr1_old(bd_up, PN);     /* lane0 <- bd_up */              \
    float dg_ = dgs;                         /* patched up_ of prev phase */   \
    float m_   = fminf(fminf(dg_, PN), up_);                                   \
    float mid_ = __builtin_amdgcn_fmed3f(dg_, PN, up_);                        \
    float mx_  = fmaxf(fmaxf(dg_, PN), up_);                                   \
    float e_   = 1.0f + __builtin_amdgcn_exp2f(m_ - mid_)                      \
                      + __builtin_amdgcn_exp2f(m_ - mx_);                      \
    float v_   = CC + m_ - __builtin_amdgcn_logf(e_);                          \
    PO = (MASKED) ? (((unsigned)(vb0 + (s)) < 512u) ? v_ : vBig) : v_;         \
    if (((s) & 3) == 0) bq.x = PO;                                             \
    if (((s) & 3) == 1) bq.y = PO;                                             \
    if (((s) & 3) == 2) bq.z = PO;                                             \
    if (((s) & 3) == 3) { bq.w = PO;                                           \
      if (lt == 63) bnd4[c + 1][(q0 + ((s) >> 2)) & 7] = bq; }                 \
    bd_up = (NQC);                                                             \
    dgs = up_;                                                                 \
    { int kl_ = kd0 + (s) + 8; if (CLAMPED) kl_ = clampi(kl_);                 \
      CC = skb[(size_t)kl_ * TLEN]; }                                          \
  }

#define SEG_BODY(MASKED, CLAMPED)                                              \
    PH(0,  c0, P, Q, nq0.x, MASKED, CLAMPED) PH(1,  c1, Q, P, nq0.y, MASKED, CLAMPED) \
    PH(2,  c2, P, Q, nq0.z, MASKED, CLAMPED) PH(3,  c3, Q, P, nq0.w, MASKED, CLAMPED) \
    PH(4,  c4, P, Q, nq1.x, MASKED, CLAMPED) PH(5,  c5, Q, P, nq1.y, MASKED, CLAMPED) \
    PH(6,  c6, P, Q, nq1.z, MASKED, CLAMPED) PH(7,  c7, Q, P, nq1.w, MASKED, CLAMPED) \
    PH(8,  c0, P, Q, nq2.x, MASKED, CLAMPED) PH(9,  c1, Q, P, nq2.y, MASKED, CLAMPED) \
    PH(10, c2, P, Q, nq2.z, MASKED, CLAMPED) PH(11, c3, Q, P, nq2.w, MASKED, CLAMPED) \
    PH(12, c4, P, Q, nq3.x, MASKED, CLAMPED) PH(13, c5, Q, P, nq3.y, MASKED, CLAMPED) \
    PH(14, c6, P, Q, nq3.z, MASKED, CLAMPED) PH(15, c7, Q, P, nq3.w, MASKED, CLAMPED)

#define PRIME(K)                                                               \
    c0 = skb[(size_t)clampi((K) + 0) * TLEN];                                  \
    c1 = skb[(size_t)clampi((K) + 1) * TLEN];                                  \
    c2 = skb[(size_t)clampi((K) + 2) * TLEN];                                  \
    c3 = skb[(size_t)clampi((K) + 3) * TLEN];                                  \
    c4 = skb[(size_t)clampi((K) + 4) * TLEN];                                  \
    c5 = skb[(size_t)clampi((K) + 5) * TLEN];                                  \
    c6 = skb[(size_t)clampi((K) + 6) * TLEN];                                  \
    c7 = skb[(size_t)clampi((K) + 7) * TLEN];

__global__ __launch_bounds__(512) void sdtw_dp(const float* __restrict__ skew,
                                               float* __restrict__ out) {
    const int b   = blockIdx.x;
    const int tid = threadIdx.x;
    const int ww  = tid >> 6;                    // hardware wave id
    const int c   = ((ww & 3) << 1) | (ww >> 2); // chunk (SIMD-aware remap)
    const int lt  = tid & 63;
    const int row = 64 * c + lt;
    const float* skb = skew + (size_t)b * (NDIAG * TLEN) + row;

    __shared__ float4 bnd4[9][8];                // [consumer chunk][quad slot]
    if (tid < 288) ((float*)bnd4)[tid] = BIGV;

    float P = BIGV, Q = BIGV;
    float vBig  = BIGV;
    float bd_up = BIGV;
    float dgs   = (tid == 0) ? 0.0f : BIGV;      // R(0,0)=0 at kd=0 (chunk0 lane0)
    float4 bq = make_float4(BIGV, BIGV, BIGV, BIGV);

    __syncthreads();                             // full barrier once (init)

    float c0, c1, c2, c3, c4, c5, c6, c7;
    PRIME(-16 * c)                               // real for chunk 0; re-primed at warm-up

    for (int s = 0; s < 71; ++s) {
        const int sw  = s - 5 * c;               // wave-uniform
        const int kd0 = 16 * (s - c);
        const int q0  = (kd0 >> 2) & 7;
        const int vb0 = kd0 - row;

        if (sw >= -1 && sw <= 35) {
            float4 nq0 = bnd4[c][q0];
            float4 nq1 = bnd4[c][(q0 + 1) & 7];
            float4 nq2 = bnd4[c][(q0 + 2) & 7];
            float4 nq3 = bnd4[c][(q0 + 3) & 7];
            if (sw == -1) { PRIME(kd0) }         // warm-up: re-prime prefetch
            if (sw >= 4 && sw <= 31) { SEG_BODY(0, 0) }   // interior
            else                     { SEG_BODY(1, 1) }   // staircase/warm-up
        } else {
            if (lt == 63) {                      // junk: keep boundary cadence
                float4 bigq = make_float4(BIGV, BIGV, BIGV, BIGV);
                bnd4[c + 1][q0]           = bigq;
                bnd4[c + 1][(q0 + 1) & 7] = bigq;
                bnd4[c + 1][(q0 + 2) & 7] = bigq;
                bnd4[c + 1][(q0 + 3) & 7] = bigq;
            }
        }
        seg_barrier_lds_only();                  // lgkmcnt-only drain + s_barrier
    }

    if (tid == 511) out[b] = Q * LN2;            // chunk 7, row 511: R'(512,512)*ln2
}

// ---------------------------------------------------------------- launcher
extern "C" void kernel_launch(void* const* d_in, const int* in_sizes, int n_in,
                              void* d_out, int out_size, void* d_ws, size_t ws_size,
                              hipStream_t stream) {
    const float* x = (const float*)d_in[0];
    const float* y = (const float*)d_in[1];
    float* outp = (float*)d_out;

    float* skew = (float*)d_ws;                  // 16,760,832 floats

    sdtw_gemm_skew<<<dim3(4, 8, BT), dim3(256), 0, stream>>>(x, y, skew);
    sdtw_dp<<<dim3(BT), dim3(512), 0, stream>>>(skew, outp);
}